// Round 19
// baseline (50.526 us; speedup 1.0000x reference)
//
#include <hip/hip_runtime.h>
#include <math.h>

typedef float        f32x2 __attribute__((ext_vector_type(2)));
typedef float        f32x4 __attribute__((ext_vector_type(4)));
typedef _Float16     f16x2 __attribute__((ext_vector_type(2)));
typedef _Float16     f16x8 __attribute__((ext_vector_type(8)));
typedef unsigned int u32;
typedef unsigned int u32x2 __attribute__((ext_vector_type(2)));
typedef unsigned int u32x4 __attribute__((ext_vector_type(4)));

// Problem constants
#define HW_    4096
#define CH_STR 8192          // channel (or o) stride in x/out = D*HW
#define B_STR  262144        // batch stride = C*D*HW
#define NPIX   131072
#define NKSTEP 18            // 576 rlen4-padded k-slots / 32
#define NSLICE 72            // 576 / 8
#define NCT    76            // +1 step pad for 2-deep descriptor prefetch
#define NBEL   (NKSTEP*2*2*64*8)   // 36864 frag elems (73,728 B)

// Scales: trig stored pre-scaled by 32 (both sides) -> u' = 1024*u; w' = 512*w
// -> acc = 2^19*oc; atan2 scale-invariant. fp16 residuals stay normal.
#define WSCALE 512.0f
#define TSCALE 32.0f

// d_ws: frag _Float16[36864] at +0 (73,728 B); ct u32[76] at +73728 (304 B).

// ---------------------------------------------------------------------------
// Prep (validated R16/R17: absmax 0.015625). Rows c padded to rlen4(c)=
// 4*(c/4+1) (total 576). frag[ks][var*2+oh][lane][j]: fp16 RNE split of
// 512*foldW at k = ks*32+8*(lane>>4)+j, o = oh*16+(lane&15).
// ct[s] = (cB0<<24)|(eB0<<16)|(cB1<<8)|eB1 byte offsets for slice s's two
// 4-segments. Zero-padded to 76 words.
// ---------------------------------------------------------------------------
__global__ void prep(const float* __restrict__ w,
                     _Float16* __restrict__ bfr,
                     u32* __restrict__ ct) {
    int idx = blockIdx.x * 256 + threadIdx.x;
    if (idx < NBEL) {
        int j    =  idx & 7;
        int lane = (idx >> 3) & 63;
        int frag = (idx >> 9) & 3;      // var*2 + oh
        int ks   =  idx >> 11;
        int var  = frag >> 1;
        int oh   = frag & 1;
        int k = ks * 32 + ((lane >> 4) << 3) + j;
        int c = 0, base = 0;
        for (; c < 32; ++c) { int rl = ((c >> 2) + 1) << 2; if (k < base + rl) break; base += rl; }
        int e = k - base;
        int o = oh * 16 + (lane & 15);
        float v = 0.0f;
        if (e <= c)
            v = (e == c) ? w[o * 1024 + c * 33]
                         : (w[o * 1024 + c * 32 + e] + w[o * 1024 + e * 32 + c]);
        v *= WSCALE;
        _Float16 h = (_Float16)v;                    // RNE hi
        if (var) h = (_Float16)(v - (float)h);       // RNE residual (lo)
        bfr[idx] = h;
    } else if (idx < NBEL + NCT) {
        int s = idx - NBEL;
        u32 v = 0;
        if (s < NSLICE) {
            int cb[2], eb[2];
            #pragma unroll
            for (int h = 0; h < 2; ++h) {
                int k = s * 8 + h * 4, c = 0, base = 0;
                for (; c < 32; ++c) { int rl = ((c >> 2) + 1) << 2; if (k < base + rl) break; base += rl; }
                cb[h] = c * 4; eb[h] = (k - base) * 4;
            }
            v = ((u32)cb[0] << 24) | ((u32)eb[0] << 16) | ((u32)cb[1] << 8) | (u32)eb[1];
        }
        ct[s] = v;
    }
}

// ---------------------------------------------------------------------------
// Main. R18 = R17 with the u-gen/split in packed f32x2 form + mantissa-AND
// hi split (uh = bitcast(u & 0xFFFFE000) = exact fp16-RTZ for normals;
// pkrtz(uh) exact; ul = u - uh exact). 14 inst/p vs 20 (-30% issue slots,
// VALU-cycles neutral if pk is half-rate) -- discriminates issue-slot-bound
// vs cycle-bound. Trig pre-scaled by 32 at prologue (kills per-step scale
// mults). Everything else identical to R17 (best: 43.6 us kernel).
// ---------------------------------------------------------------------------
#define TPB   256
#define TSTR  68    // trig row stride (dwords) = 272 B, multiple of 16

__device__ __forceinline__ f16x8 pack8(u32 a, u32 b, u32 c, u32 d) {
    u32x4 t = {a, b, c, d};
    return __builtin_bit_cast(f16x8, t);
}
__device__ __forceinline__ u32 pkrtz_u(float a, float b) {
    return __builtin_bit_cast(u32, __builtin_amdgcn_cvt_pkrtz(a, b));
}

// Branch-free atan2 (validated R17): ~17 VALU, err ~1e-6 rad.
__device__ __forceinline__ float fast_atan2(float y, float x) {
    const float ax = __builtin_fabsf(x), ay = __builtin_fabsf(y);
    const float mx = fmaxf(ax, ay), mn = fminf(ax, ay);
    const float t  = mn * __builtin_amdgcn_rcpf(fmaxf(mx, 1e-37f));
    const float s  = t * t;
    float p = fmaf(s, -0.0117212f, 0.05265332f);
    p = fmaf(s, p, -0.11643287f);
    p = fmaf(s, p,  0.19354346f);
    p = fmaf(s, p, -0.33262347f);
    p = fmaf(s, p,  0.99997726f);
    float a = t * p;
    a = (ay > ax) ? (1.5707963268f - a) : a;
    a = (x < 0.0f) ? (3.1415926536f - a) : a;
    return __builtin_copysignf(a, y);
}

__global__ __launch_bounds__(TPB, 4) void mfma_bilinear(
    const float* __restrict__ x,
    const _Float16* __restrict__ bfr,
    const u32* __restrict__ ct,
    const float* __restrict__ bias,
    float* __restrict__ out)
{
    __shared__ float trig[64 * TSTR];   // 17,408 B

    const int lane = threadIdx.x & 63;
    const int wv   = threadIdx.x >> 6;       // wave id 0..3
    const int lg   = lane >> 4;              // k-subgroup 0..3
    const int lidm = lane & 15;              // A-row / B-col within fragment
    const int P0   = blockIdx.x * 64;
    const int b    = P0 >> 13;
    const int d    = (P0 >> 12) & 1;
    const int hw0  = P0 & 4095;              // 64-aligned, block stays in (b,d)
    const int obase = b * B_STR + d * HW_ + hw0;   // + px + (c|o)*CH_STR

    const int px = wv * 16 + lidm;           // block-local pixel (my A-row)
    float* tp = trig + px * TSTR;
    const char* tb = (const char*)tp;        // byte base of my trig row

    // ---- trig prologue: pre-scaled by 32 (both u-gen operands) ----
    #pragma unroll
    for (int m = 0; m < 8; ++m) {
        int c = lg * 8 + m;
        float xv = x[obase + px + c * CH_STR];
        float s, co; __sincosf(xv, &s, &co);
        tp[c]      = co * TSCALE;
        tp[32 + c] = s * TSCALE;
    }
    // same-wave DS ordering makes the reads below safe without a barrier.

    f32x4 acc_r[2] = {{0.f,0.f,0.f,0.f}, {0.f,0.f,0.f,0.f}};
    f32x4 acc_i[2] = {{0.f,0.f,0.f,0.f}, {0.f,0.f,0.f,0.f}};

    // Streaming pointers: uniform base + (lane/lg) voffset + imm offsets.
    const char* ubp = (const char*)bfr;      // step-ks B block at ubp (+= 4096)
    const char* uct = (const char*)ct;       // word(ks) at uct (+= 16)
    const int lo16 = lane * 16;
    const int lg4  = lg * 4;

#define LDB(OFF)      (*(const f16x8*)(ubp + lo16 + (OFF)))
#define LDCT(OFF)     (*(const u32*)(uct + lg4 + (OFF)))
#define LOAD_TRIG(ST, CC0, SC0, CE0, SE0, CC1, SC1, CE1, SE1) do { \
    const u32 st_ = (ST); \
    const int cB0 = (int)(st_ >> 24); \
    const int eB0 = (int)((st_ >> 16) & 0xffu); \
    const int cB1 = (int)((st_ >> 8) & 0xffu); \
    const int eB1 = (int)(st_ & 0xffu); \
    CC0 = *(const float*)(tb + cB0); \
    SC0 = *(const float*)(tb + 128 + cB0); \
    CE0 = *(const f32x4*)(tb + eB0); \
    SE0 = *(const f32x4*)(tb + 128 + eB0); \
    CC1 = *(const float*)(tb + cB1); \
    SC1 = *(const float*)(tb + 128 + cB1); \
    CE1 = *(const f32x4*)(tb + eB1); \
    SE1 = *(const f32x4*)(tb + 128 + eB1); \
} while (0)

// One k-step: packed u-gen + AND hi split + exact residual + 12 MFMA.
#define COMPUTE_STEP(CC0, SC0, CE0, SE0, CC1, SC1, CE1, SE1, BH0, BH1, BL0, BL1) do { \
    const u32x2 hmask = {0xFFFFE000u, 0xFFFFE000u}; \
    u32 hr[4], hi[4], lr[4], li[4]; \
    _Pragma("unroll") \
    for (int p = 0; p < 4; ++p) { \
        const float ccv = (p < 2) ? (CC0) : (CC1); \
        const float scv = (p < 2) ? (SC0) : (SC1); \
        const int i0 = (p & 1) * 2; \
        const f32x2 cc2 = {ccv, ccv}; \
        const f32x2 sc2 = {scv, scv}; \
        const f32x2 ce2 = (p < 2) ? (f32x2){(CE0)[i0], (CE0)[i0 + 1]} \
                                  : (f32x2){(CE1)[i0], (CE1)[i0 + 1]}; \
        const f32x2 se2 = (p < 2) ? (f32x2){(SE0)[i0], (SE0)[i0 + 1]} \
                                  : (f32x2){(SE1)[i0], (SE1)[i0 + 1]}; \
        const f32x2 ur = __builtin_elementwise_fma(cc2, ce2, -(sc2 * se2)); \
        const f32x2 ui = __builtin_elementwise_fma(cc2, se2,  (sc2 * ce2)); \
        const f32x2 uhr = __builtin_bit_cast(f32x2, __builtin_bit_cast(u32x2, ur) & hmask); \
        const f32x2 uhi = __builtin_bit_cast(f32x2, __builtin_bit_cast(u32x2, ui) & hmask); \
        const f32x2 ulr = ur - uhr;   /* exact */ \
        const f32x2 uli = ui - uhi; \
        hr[p] = pkrtz_u(uhr[0], uhr[1]);   /* exact: uh is fp16-representable */ \
        hi[p] = pkrtz_u(uhi[0], uhi[1]); \
        lr[p] = pkrtz_u(ulr[0], ulr[1]); \
        li[p] = pkrtz_u(uli[0], uli[1]); \
    } \
    const f16x8 ahr = pack8(hr[0], hr[1], hr[2], hr[3]); \
    const f16x8 ahi = pack8(hi[0], hi[1], hi[2], hi[3]); \
    const f16x8 alr = pack8(lr[0], lr[1], lr[2], lr[3]); \
    const f16x8 ali = pack8(li[0], li[1], li[2], li[3]); \
    acc_r[0] = __builtin_amdgcn_mfma_f32_16x16x32_f16(ahr, BH0, acc_r[0], 0, 0, 0); \
    acc_i[0] = __builtin_amdgcn_mfma_f32_16x16x32_f16(ahi, BH0, acc_i[0], 0, 0, 0); \
    acc_r[1] = __builtin_amdgcn_mfma_f32_16x16x32_f16(ahr, BH1, acc_r[1], 0, 0, 0); \
    acc_i[1] = __builtin_amdgcn_mfma_f32_16x16x32_f16(ahi, BH1, acc_i[1], 0, 0, 0); \
    acc_r[0] = __builtin_amdgcn_mfma_f32_16x16x32_f16(ahr, BL0, acc_r[0], 0, 0, 0); \
    acc_i[0] = __builtin_amdgcn_mfma_f32_16x16x32_f16(ahi, BL0, acc_i[0], 0, 0, 0); \
    acc_r[1] = __builtin_amdgcn_mfma_f32_16x16x32_f16(ahr, BL1, acc_r[1], 0, 0, 0); \
    acc_i[1] = __builtin_amdgcn_mfma_f32_16x16x32_f16(ahi, BL1, acc_i[1], 0, 0, 0); \
    acc_r[0] = __builtin_amdgcn_mfma_f32_16x16x32_f16(alr, BH0, acc_r[0], 0, 0, 0); \
    acc_i[0] = __builtin_amdgcn_mfma_f32_16x16x32_f16(ali, BH0, acc_i[0], 0, 0, 0); \
    acc_r[1] = __builtin_amdgcn_mfma_f32_16x16x32_f16(alr, BH1, acc_r[1], 0, 0, 0); \
    acc_i[1] = __builtin_amdgcn_mfma_f32_16x16x32_f16(ali, BH1, acc_i[1], 0, 0, 0); \
} while (0)

    // ---- pipeline prologue: step-0 state + descriptor for step 1 ----
    f16x8 bh0 = LDB(0), bh1 = LDB(1024), bl0 = LDB(2048), bl1 = LDB(3072);
    float cc0, sc0, cc1, sc1; f32x4 ce0, se0, ce1, se1;
    LOAD_TRIG(LDCT(0), cc0, sc0, ce0, se0, cc1, sc1, ce1, se1);
    u32 stN = LDCT(16);
    ubp += 4096;                         // -> step 1 block

    #pragma unroll 4
    for (int ks = 0; ks < NKSTEP - 1; ++ks) {
        // prefetch step ks+1 (B block at ubp; trig via stN; word for ks+2)
        f16x8 nbh0 = LDB(0), nbh1 = LDB(1024), nbl0 = LDB(2048), nbl1 = LDB(3072);
        float ncc0, nsc0, ncc1, nsc1; f32x4 nce0, nse0, nce1, nse1;
        LOAD_TRIG(stN, ncc0, nsc0, nce0, nse0, ncc1, nsc1, nce1, nse1);
        u32 stN2 = LDCT(32);             // word(ks+2); padded table keeps in-bounds

        COMPUTE_STEP(cc0, sc0, ce0, se0, cc1, sc1, ce1, se1, bh0, bh1, bl0, bl1);

        bh0 = nbh0; bh1 = nbh1; bl0 = nbl0; bl1 = nbl1;
        cc0 = ncc0; sc0 = nsc0; cc1 = ncc1; sc1 = nsc1;
        ce0 = nce0; se0 = nse0; ce1 = nce1; se1 = nse1;
        stN = stN2;
        ubp += 4096; uct += 16;
    }
    // peeled final step (no prefetch, no clamps anywhere)
    COMPUTE_STEP(cc0, sc0, ce0, se0, cc1, sc1, ce1, se1, bh0, bh1, bl0, bl1);

    // ---- epilogue: C/D (m89): col o = oh*16 + (lane&15), row px = 4*lg + q ----
    #pragma unroll
    for (int oh = 0; oh < 2; ++oh) {
        const int o = oh * 16 + lidm;
        const float bo = bias[o];
        #pragma unroll
        for (int q = 0; q < 4; ++q) {
            const int pxr = wv * 16 + lg * 4 + q;
            out[obase + pxr + o * CH_STR] = fast_atan2(acc_i[oh][q], acc_r[oh][q]) + bo;
        }
    }
#undef LDB
#undef LDCT
#undef LOAD_TRIG
#undef COMPUTE_STEP
}

// ---------------------------------------------------------------------------
extern "C" void kernel_launch(void* const* d_in, const int* in_sizes, int n_in,
                              void* d_out, int out_size, void* d_ws, size_t ws_size,
                              hipStream_t stream) {
    const float* x    = (const float*)d_in[0];
    const float* w    = (const float*)d_in[1];
    const float* bias = (const float*)d_in[2];
    float* out        = (float*)d_out;
    _Float16* bfr = (_Float16*)d_ws;                  // 73,728 B
    u32*      ct  = (u32*)((char*)d_ws + 73728);      // 304 B

    {
        int n = NBEL + NCT;
        prep<<<(n + 255) / 256, 256, 0, stream>>>(w, bfr, ct);
    }
    {
        int grid = NPIX / 64;   // 2048 blocks x 4 waves
        mfma_bilinear<<<grid, TPB, 0, stream>>>(x, bfr, ct, bias, out);
    }
}

// Round 20
// 49.182 us; speedup vs baseline: 1.0273x; 1.0273x over previous
//
#include <hip/hip_runtime.h>
#include <math.h>

typedef float        f32x4 __attribute__((ext_vector_type(4)));
typedef _Float16     f16x2 __attribute__((ext_vector_type(2)));
typedef _Float16     f16x8 __attribute__((ext_vector_type(8)));
typedef unsigned int u32;
typedef unsigned int u32x4 __attribute__((ext_vector_type(4)));

// Problem constants
#define HW_    4096
#define CH_STR 8192          // channel (or o) stride in x/out = D*HW
#define B_STR  262144        // batch stride = C*D*HW
#define NPIX   131072
#define NKSTEP 18            // 576 rlen4-padded k-slots / 32
#define NSLICE 72            // 576 / 8
#define NCT    76            // +1 step pad for 2-deep descriptor prefetch
#define NBEL   (NKSTEP*2*2*64*8)   // 36864 frag elems (73,728 B)

// Scales: u' = 1024*u, w' = 512*w  ->  acc = 2^19*oc; atan2 scale-invariant.
#define WSCALE 512.0f
#define USCALE 1024.0f

// d_ws: frag _Float16[36864] at +0 (73,728 B); ct u32[76] at +73728 (304 B).

// ---------------------------------------------------------------------------
// Prep (validated R16/R17: absmax 0.015625). Rows c padded to rlen4(c)=
// 4*(c/4+1) (total 576). frag[ks][var*2+oh][lane][j]: fp16 RNE split of
// 512*foldW at k = ks*32+8*(lane>>4)+j, o = oh*16+(lane&15).
// ct[s] = (cB0<<24)|(eB0<<16)|(cB1<<8)|eB1 byte offsets for slice s's two
// 4-segments. Zero-padded to 76 words.
// ---------------------------------------------------------------------------
__global__ void prep(const float* __restrict__ w,
                     _Float16* __restrict__ bfr,
                     u32* __restrict__ ct) {
    int idx = blockIdx.x * 256 + threadIdx.x;
    if (idx < NBEL) {
        int j    =  idx & 7;
        int lane = (idx >> 3) & 63;
        int frag = (idx >> 9) & 3;      // var*2 + oh
        int ks   =  idx >> 11;
        int var  = frag >> 1;
        int oh   = frag & 1;
        int k = ks * 32 + ((lane >> 4) << 3) + j;
        int c = 0, base = 0;
        for (; c < 32; ++c) { int rl = ((c >> 2) + 1) << 2; if (k < base + rl) break; base += rl; }
        int e = k - base;
        int o = oh * 16 + (lane & 15);
        float v = 0.0f;
        if (e <= c)
            v = (e == c) ? w[o * 1024 + c * 33]
                         : (w[o * 1024 + c * 32 + e] + w[o * 1024 + e * 32 + c]);
        v *= WSCALE;
        _Float16 h = (_Float16)v;                    // RNE hi
        if (var) h = (_Float16)(v - (float)h);       // RNE residual (lo)
        bfr[idx] = h;
    } else if (idx < NBEL + NCT) {
        int s = idx - NBEL;
        u32 v = 0;
        if (s < NSLICE) {
            int cb[2], eb[2];
            #pragma unroll
            for (int h = 0; h < 2; ++h) {
                int k = s * 8 + h * 4, c = 0, base = 0;
                for (; c < 32; ++c) { int rl = ((c >> 2) + 1) << 2; if (k < base + rl) break; base += rl; }
                cb[h] = c * 4; eb[h] = (k - base) * 4;
            }
            v = ((u32)cb[0] << 24) | ((u32)eb[0] << 16) | ((u32)cb[1] << 8) | (u32)eb[1];
        }
        ct[s] = v;
    }
}

// ---------------------------------------------------------------------------
// Main. R19 = R17 verbatim (best: 43.6 us kernel, VGPR 40) with ONE change:
// __launch_bounds__(256, 2) -- doubles the RA's register budget so the
// written 2-deep software pipeline (B-frags + trig for step ks+1, ~80 live
// regs) can actually be HELD in registers instead of the loads being sunk
// to just-before-use (convoy stall: every wave waits the full L1/L2 latency
// every step; matches the measured ~766 cyc/step vs ~400 cyc of pipe work).
// ---------------------------------------------------------------------------
#define TPB   256
#define TSTR  68    // trig row stride (dwords) = 272 B, multiple of 16

__device__ __forceinline__ f16x8 pack8(u32 a, u32 b, u32 c, u32 d) {
    u32x4 t = {a, b, c, d};
    return __builtin_bit_cast(f16x8, t);
}
__device__ __forceinline__ u32 pkrtz_u(float a, float b) {
    return __builtin_bit_cast(u32, __builtin_amdgcn_cvt_pkrtz(a, b));
}

// Branch-free atan2 (validated R17): ~17 VALU, err ~1e-6 rad.
__device__ __forceinline__ float fast_atan2(float y, float x) {
    const float ax = __builtin_fabsf(x), ay = __builtin_fabsf(y);
    const float mx = fmaxf(ax, ay), mn = fminf(ax, ay);
    const float t  = mn * __builtin_amdgcn_rcpf(fmaxf(mx, 1e-37f));
    const float s  = t * t;
    float p = fmaf(s, -0.0117212f, 0.05265332f);
    p = fmaf(s, p, -0.11643287f);
    p = fmaf(s, p,  0.19354346f);
    p = fmaf(s, p, -0.33262347f);
    p = fmaf(s, p,  0.99997726f);
    float a = t * p;
    a = (ay > ax) ? (1.5707963268f - a) : a;
    a = (x < 0.0f) ? (3.1415926536f - a) : a;
    return __builtin_copysignf(a, y);
}

__global__ __launch_bounds__(TPB, 2) void mfma_bilinear(
    const float* __restrict__ x,
    const _Float16* __restrict__ bfr,
    const u32* __restrict__ ct,
    const float* __restrict__ bias,
    float* __restrict__ out)
{
    __shared__ float trig[64 * TSTR];   // 17,408 B

    const int lane = threadIdx.x & 63;
    const int wv   = threadIdx.x >> 6;       // wave id 0..3
    const int lg   = lane >> 4;              // k-subgroup 0..3
    const int lidm = lane & 15;              // A-row / B-col within fragment
    const int P0   = blockIdx.x * 64;
    const int b    = P0 >> 13;
    const int d    = (P0 >> 12) & 1;
    const int hw0  = P0 & 4095;              // 64-aligned, block stays in (b,d)
    const int obase = b * B_STR + d * HW_ + hw0;   // + px + (c|o)*CH_STR

    const int px = wv * 16 + lidm;           // block-local pixel (my A-row)
    float* tp = trig + px * TSTR;
    const char* tb = (const char*)tp;        // byte base of my trig row

    // ---- trig prologue: 4 lanes (lg=0..3) cover the 32 channels of px ----
    #pragma unroll
    for (int m = 0; m < 8; ++m) {
        int c = lg * 8 + m;
        float xv = x[obase + px + c * CH_STR];
        float s, co; __sincosf(xv, &s, &co);
        tp[c]      = co;
        tp[32 + c] = s;
    }
    // same-wave DS ordering makes the reads below safe without a barrier.

    f32x4 acc_r[2] = {{0.f,0.f,0.f,0.f}, {0.f,0.f,0.f,0.f}};
    f32x4 acc_i[2] = {{0.f,0.f,0.f,0.f}, {0.f,0.f,0.f,0.f}};

    // Streaming pointers: uniform base + (lane/lg) voffset + imm offsets.
    const char* ubp = (const char*)bfr;      // step-ks B block at ubp (+= 4096)
    const char* uct = (const char*)ct;       // word(ks) at uct (+= 16)
    const int lo16 = lane * 16;
    const int lg4  = lg * 4;

#define LDB(OFF)      (*(const f16x8*)(ubp + lo16 + (OFF)))
#define LDCT(OFF)     (*(const u32*)(uct + lg4 + (OFF)))
#define LOAD_TRIG(ST, CC0, SC0, CE0, SE0, CC1, SC1, CE1, SE1) do { \
    const u32 st_ = (ST); \
    const int cB0 = (int)(st_ >> 24); \
    const int eB0 = (int)((st_ >> 16) & 0xffu); \
    const int cB1 = (int)((st_ >> 8) & 0xffu); \
    const int eB1 = (int)(st_ & 0xffu); \
    CC0 = *(const float*)(tb + cB0); \
    SC0 = *(const float*)(tb + 128 + cB0); \
    CE0 = *(const f32x4*)(tb + eB0); \
    SE0 = *(const f32x4*)(tb + 128 + eB0); \
    CC1 = *(const float*)(tb + cB1); \
    SC1 = *(const float*)(tb + 128 + cB1); \
    CE1 = *(const f32x4*)(tb + eB1); \
    SE1 = *(const f32x4*)(tb + 128 + eB1); \
} while (0)

// One k-step: u-gen (2 segments) + fp16 RTZ 2-split + 12 MFMA.
#define COMPUTE_STEP(CC0, SC0, CE0, SE0, CC1, SC1, CE1, SE1, BH0, BH1, BL0, BL1) do { \
    const float cs0c = (CC0) * USCALE, cs0s = (SC0) * USCALE; \
    const float cs1c = (CC1) * USCALE, cs1s = (SC1) * USCALE; \
    u32 hr[4], hi[4], lr[4], li[4]; \
    _Pragma("unroll") \
    for (int p = 0; p < 4; ++p) { \
        const float ccs = (p < 2) ? cs0c : cs1c; \
        const float scs = (p < 2) ? cs0s : cs1s; \
        const int i0 = (p & 1) * 2; \
        const float cea = (p < 2) ? (CE0)[i0]     : (CE1)[i0]; \
        const float sea = (p < 2) ? (SE0)[i0]     : (SE1)[i0]; \
        const float ceb = (p < 2) ? (CE0)[i0 + 1] : (CE1)[i0 + 1]; \
        const float seb = (p < 2) ? (SE0)[i0 + 1] : (SE1)[i0 + 1]; \
        const float ur0 = fmaf(ccs, cea, -(scs * sea)); \
        const float ui0 = fmaf(ccs, sea,   scs * cea); \
        const float ur1 = fmaf(ccs, ceb, -(scs * seb)); \
        const float ui1 = fmaf(ccs, seb,   scs * ceb); \
        hr[p] = pkrtz_u(ur0, ur1); \
        hi[p] = pkrtz_u(ui0, ui1); \
        const f16x2 h2r = __builtin_bit_cast(f16x2, hr[p]); \
        const f16x2 h2i = __builtin_bit_cast(f16x2, hi[p]); \
        lr[p] = pkrtz_u(ur0 - (float)h2r[0], ur1 - (float)h2r[1]); \
        li[p] = pkrtz_u(ui0 - (float)h2i[0], ui1 - (float)h2i[1]); \
    } \
    const f16x8 ahr = pack8(hr[0], hr[1], hr[2], hr[3]); \
    const f16x8 ahi = pack8(hi[0], hi[1], hi[2], hi[3]); \
    const f16x8 alr = pack8(lr[0], lr[1], lr[2], lr[3]); \
    const f16x8 ali = pack8(li[0], li[1], li[2], li[3]); \
    acc_r[0] = __builtin_amdgcn_mfma_f32_16x16x32_f16(ahr, BH0, acc_r[0], 0, 0, 0); \
    acc_i[0] = __builtin_amdgcn_mfma_f32_16x16x32_f16(ahi, BH0, acc_i[0], 0, 0, 0); \
    acc_r[1] = __builtin_amdgcn_mfma_f32_16x16x32_f16(ahr, BH1, acc_r[1], 0, 0, 0); \
    acc_i[1] = __builtin_amdgcn_mfma_f32_16x16x32_f16(ahi, BH1, acc_i[1], 0, 0, 0); \
    acc_r[0] = __builtin_amdgcn_mfma_f32_16x16x32_f16(ahr, BL0, acc_r[0], 0, 0, 0); \
    acc_i[0] = __builtin_amdgcn_mfma_f32_16x16x32_f16(ahi, BL0, acc_i[0], 0, 0, 0); \
    acc_r[1] = __builtin_amdgcn_mfma_f32_16x16x32_f16(ahr, BL1, acc_r[1], 0, 0, 0); \
    acc_i[1] = __builtin_amdgcn_mfma_f32_16x16x32_f16(ahi, BL1, acc_i[1], 0, 0, 0); \
    acc_r[0] = __builtin_amdgcn_mfma_f32_16x16x32_f16(alr, BH0, acc_r[0], 0, 0, 0); \
    acc_i[0] = __builtin_amdgcn_mfma_f32_16x16x32_f16(ali, BH0, acc_i[0], 0, 0, 0); \
    acc_r[1] = __builtin_amdgcn_mfma_f32_16x16x32_f16(alr, BH1, acc_r[1], 0, 0, 0); \
    acc_i[1] = __builtin_amdgcn_mfma_f32_16x16x32_f16(ali, BH1, acc_i[1], 0, 0, 0); \
} while (0)

    // ---- pipeline prologue: step-0 state + descriptor for step 1 ----
    f16x8 bh0 = LDB(0), bh1 = LDB(1024), bl0 = LDB(2048), bl1 = LDB(3072);
    float cc0, sc0, cc1, sc1; f32x4 ce0, se0, ce1, se1;
    LOAD_TRIG(LDCT(0), cc0, sc0, ce0, se0, cc1, sc1, ce1, se1);
    u32 stN = LDCT(16);
    ubp += 4096;                         // -> step 1 block

    #pragma unroll 4
    for (int ks = 0; ks < NKSTEP - 1; ++ks) {
        // prefetch step ks+1 (B block at ubp; trig via stN; word for ks+2)
        f16x8 nbh0 = LDB(0), nbh1 = LDB(1024), nbl0 = LDB(2048), nbl1 = LDB(3072);
        float ncc0, nsc0, ncc1, nsc1; f32x4 nce0, nse0, nce1, nse1;
        LOAD_TRIG(stN, ncc0, nsc0, nce0, nse0, ncc1, nsc1, nce1, nse1);
        u32 stN2 = LDCT(32);             // word(ks+2); padded table keeps in-bounds

        COMPUTE_STEP(cc0, sc0, ce0, se0, cc1, sc1, ce1, se1, bh0, bh1, bl0, bl1);

        bh0 = nbh0; bh1 = nbh1; bl0 = nbl0; bl1 = nbl1;
        cc0 = ncc0; sc0 = nsc0; cc1 = ncc1; sc1 = nsc1;
        ce0 = nce0; se0 = nse0; ce1 = nce1; se1 = nse1;
        stN = stN2;
        ubp += 4096; uct += 16;
    }
    // peeled final step (no prefetch, no clamps anywhere)
    COMPUTE_STEP(cc0, sc0, ce0, se0, cc1, sc1, ce1, se1, bh0, bh1, bl0, bl1);

    // ---- epilogue: C/D (m89): col o = oh*16 + (lane&15), row px = 4*lg + q ----
    #pragma unroll
    for (int oh = 0; oh < 2; ++oh) {
        const int o = oh * 16 + lidm;
        const float bo = bias[o];
        #pragma unroll
        for (int q = 0; q < 4; ++q) {
            const int pxr = wv * 16 + lg * 4 + q;
            out[obase + pxr + o * CH_STR] = fast_atan2(acc_i[oh][q], acc_r[oh][q]) + bo;
        }
    }
#undef LDB
#undef LDCT
#undef LOAD_TRIG
#undef COMPUTE_STEP
}

// ---------------------------------------------------------------------------
extern "C" void kernel_launch(void* const* d_in, const int* in_sizes, int n_in,
                              void* d_out, int out_size, void* d_ws, size_t ws_size,
                              hipStream_t stream) {
    const float* x    = (const float*)d_in[0];
    const float* w    = (const float*)d_in[1];
    const float* bias = (const float*)d_in[2];
    float* out        = (float*)d_out;
    _Float16* bfr = (_Float16*)d_ws;                  // 73,728 B
    u32*      ct  = (u32*)((char*)d_ws + 73728);      // 304 B

    {
        int n = NBEL + NCT;
        prep<<<(n + 255) / 256, 256, 0, stream>>>(w, bfr, ct);
    }
    {
        int grid = NPIX / 64;   // 2048 blocks x 4 waves
        mfma_bilinear<<<grid, TPB, 0, stream>>>(x, bfr, ct, bias, out);
    }
}

// Round 21
// 48.715 us; speedup vs baseline: 1.0372x; 1.0096x over previous
//
#include <hip/hip_runtime.h>
#include <math.h>

typedef float        f32x4 __attribute__((ext_vector_type(4)));
typedef _Float16     f16x2 __attribute__((ext_vector_type(2)));
typedef _Float16     f16x8 __attribute__((ext_vector_type(8)));
typedef unsigned int u32;
typedef unsigned int u32x4 __attribute__((ext_vector_type(4)));

// Problem constants
#define HW_    4096
#define CH_STR 8192          // channel (or o) stride in x/out = D*HW
#define B_STR  262144        // batch stride = C*D*HW
#define NPIX   131072
#define NKSTEP 18            // 576 rlen4-padded k-slots / 32
#define NSLICE 72            // 576 / 8
#define NCT    76            // +1 step pad for 2-deep descriptor prefetch
#define NBEL   (NKSTEP*2*2*64*8)   // 36864 frag elems (73,728 B)

// Scales: u' = 1024*u, w' = 512*w  ->  acc = 2^19*oc; atan2 scale-invariant.
#define WSCALE 512.0f
#define USCALE 1024.0f

// d_ws: frag _Float16[36864] at +0 (73,728 B); ct u32[76] at +73728 (304 B).

// ---------------------------------------------------------------------------
// Prep (validated R16-R19: absmax 0.015625). Rows c padded to rlen4(c)=
// 4*(c/4+1) (total 576). frag[ks][var*2+oh][lane][j]: fp16 RNE split of
// 512*foldW at k = ks*32+8*(lane>>4)+j, o = oh*16+(lane&15).
// ct[s] = (cB0<<24)|(eB0<<16)|(cB1<<8)|eB1 byte offsets for slice s's two
// 4-segments. Zero-padded to 76 words.
// ---------------------------------------------------------------------------
__global__ void prep(const float* __restrict__ w,
                     _Float16* __restrict__ bfr,
                     u32* __restrict__ ct) {
    int idx = blockIdx.x * 256 + threadIdx.x;
    if (idx < NBEL) {
        int j    =  idx & 7;
        int lane = (idx >> 3) & 63;
        int frag = (idx >> 9) & 3;      // var*2 + oh
        int ks   =  idx >> 11;
        int var  = frag >> 1;
        int oh   = frag & 1;
        int k = ks * 32 + ((lane >> 4) << 3) + j;
        int c = 0, base = 0;
        for (; c < 32; ++c) { int rl = ((c >> 2) + 1) << 2; if (k < base + rl) break; base += rl; }
        int e = k - base;
        int o = oh * 16 + (lane & 15);
        float v = 0.0f;
        if (e <= c)
            v = (e == c) ? w[o * 1024 + c * 33]
                         : (w[o * 1024 + c * 32 + e] + w[o * 1024 + e * 32 + c]);
        v *= WSCALE;
        _Float16 h = (_Float16)v;                    // RNE hi
        if (var) h = (_Float16)(v - (float)h);       // RNE residual (lo)
        bfr[idx] = h;
    } else if (idx < NBEL + NCT) {
        int s = idx - NBEL;
        u32 v = 0;
        if (s < NSLICE) {
            int cb[2], eb[2];
            #pragma unroll
            for (int h = 0; h < 2; ++h) {
                int k = s * 8 + h * 4, c = 0, base = 0;
                for (; c < 32; ++c) { int rl = ((c >> 2) + 1) << 2; if (k < base + rl) break; base += rl; }
                cb[h] = c * 4; eb[h] = (k - base) * 4;
            }
            v = ((u32)cb[0] << 24) | ((u32)eb[0] << 16) | ((u32)cb[1] << 8) | (u32)eb[1];
        }
        ct[s] = v;
    }
}

// ---------------------------------------------------------------------------
// Main. R20 = R17 verbatim (best: 43.6 us kernel) with the split residual
// computed by v_fma_mix_f32 (ul = -1.0 * f16(uh) + u, f16 operand read
// directly from the packed register via op_sel) -- replaces 2 cvt + 2 sub
// per float-pair with 2 fma_mix: -16 VALU/step, exact arithmetic.
// ---------------------------------------------------------------------------
#define TPB   256
#define TSTR  68    // trig row stride (dwords) = 272 B, multiple of 16

__device__ __forceinline__ f16x8 pack8(u32 a, u32 b, u32 c, u32 d) {
    u32x4 t = {a, b, c, d};
    return __builtin_bit_cast(f16x8, t);
}
__device__ __forceinline__ u32 pkrtz_u(float a, float b) {
    return __builtin_bit_cast(u32, __builtin_amdgcn_cvt_pkrtz(a, b));
}

// ul = u - (f32)(f16 half of H)   [exact; Sterbenz], one VALU op.
__device__ __forceinline__ float fmix_sub_lo(u32 H, float u) {
    float r;
    asm("v_fma_mix_f32 %0, %1, -1.0, %2 op_sel:[0,0,0] op_sel_hi:[1,0,0]"
        : "=v"(r) : "v"(H), "v"(u));
    return r;
}
__device__ __forceinline__ float fmix_sub_hi(u32 H, float u) {
    float r;
    asm("v_fma_mix_f32 %0, %1, -1.0, %2 op_sel:[1,0,0] op_sel_hi:[1,0,0]"
        : "=v"(r) : "v"(H), "v"(u));
    return r;
}

// Branch-free atan2 (validated R17): ~17 VALU, err ~1e-6 rad.
__device__ __forceinline__ float fast_atan2(float y, float x) {
    const float ax = __builtin_fabsf(x), ay = __builtin_fabsf(y);
    const float mx = fmaxf(ax, ay), mn = fminf(ax, ay);
    const float t  = mn * __builtin_amdgcn_rcpf(fmaxf(mx, 1e-37f));
    const float s  = t * t;
    float p = fmaf(s, -0.0117212f, 0.05265332f);
    p = fmaf(s, p, -0.11643287f);
    p = fmaf(s, p,  0.19354346f);
    p = fmaf(s, p, -0.33262347f);
    p = fmaf(s, p,  0.99997726f);
    float a = t * p;
    a = (ay > ax) ? (1.5707963268f - a) : a;
    a = (x < 0.0f) ? (3.1415926536f - a) : a;
    return __builtin_copysignf(a, y);
}

__global__ __launch_bounds__(TPB, 4) void mfma_bilinear(
    const float* __restrict__ x,
    const _Float16* __restrict__ bfr,
    const u32* __restrict__ ct,
    const float* __restrict__ bias,
    float* __restrict__ out)
{
    __shared__ float trig[64 * TSTR];   // 17,408 B

    const int lane = threadIdx.x & 63;
    const int wv   = threadIdx.x >> 6;       // wave id 0..3
    const int lg   = lane >> 4;              // k-subgroup 0..3
    const int lidm = lane & 15;              // A-row / B-col within fragment
    const int P0   = blockIdx.x * 64;
    const int b    = P0 >> 13;
    const int d    = (P0 >> 12) & 1;
    const int hw0  = P0 & 4095;              // 64-aligned, block stays in (b,d)
    const int obase = b * B_STR + d * HW_ + hw0;   // + px + (c|o)*CH_STR

    const int px = wv * 16 + lidm;           // block-local pixel (my A-row)
    float* tp = trig + px * TSTR;
    const char* tb = (const char*)tp;        // byte base of my trig row

    // ---- trig prologue: 4 lanes (lg=0..3) cover the 32 channels of px ----
    #pragma unroll
    for (int m = 0; m < 8; ++m) {
        int c = lg * 8 + m;
        float xv = x[obase + px + c * CH_STR];
        float s, co; __sincosf(xv, &s, &co);
        tp[c]      = co;
        tp[32 + c] = s;
    }
    // same-wave DS ordering makes the reads below safe without a barrier.

    f32x4 acc_r[2] = {{0.f,0.f,0.f,0.f}, {0.f,0.f,0.f,0.f}};
    f32x4 acc_i[2] = {{0.f,0.f,0.f,0.f}, {0.f,0.f,0.f,0.f}};

    // Streaming pointers: uniform base + (lane/lg) voffset + imm offsets.
    const char* ubp = (const char*)bfr;      // step-ks B block at ubp (+= 4096)
    const char* uct = (const char*)ct;       // word(ks) at uct (+= 16)
    const int lo16 = lane * 16;
    const int lg4  = lg * 4;

#define LDB(OFF)      (*(const f16x8*)(ubp + lo16 + (OFF)))
#define LDCT(OFF)     (*(const u32*)(uct + lg4 + (OFF)))
#define LOAD_TRIG(ST, CC0, SC0, CE0, SE0, CC1, SC1, CE1, SE1) do { \
    const u32 st_ = (ST); \
    const int cB0 = (int)(st_ >> 24); \
    const int eB0 = (int)((st_ >> 16) & 0xffu); \
    const int cB1 = (int)((st_ >> 8) & 0xffu); \
    const int eB1 = (int)(st_ & 0xffu); \
    CC0 = *(const float*)(tb + cB0); \
    SC0 = *(const float*)(tb + 128 + cB0); \
    CE0 = *(const f32x4*)(tb + eB0); \
    SE0 = *(const f32x4*)(tb + 128 + eB0); \
    CC1 = *(const float*)(tb + cB1); \
    SC1 = *(const float*)(tb + 128 + cB1); \
    CE1 = *(const f32x4*)(tb + eB1); \
    SE1 = *(const f32x4*)(tb + 128 + eB1); \
} while (0)

// One k-step: u-gen (2 segments) + fp16 split (fma_mix residual) + 12 MFMA.
#define COMPUTE_STEP(CC0, SC0, CE0, SE0, CC1, SC1, CE1, SE1, BH0, BH1, BL0, BL1) do { \
    const float cs0c = (CC0) * USCALE, cs0s = (SC0) * USCALE; \
    const float cs1c = (CC1) * USCALE, cs1s = (SC1) * USCALE; \
    u32 hr[4], hi[4], lr[4], li[4]; \
    _Pragma("unroll") \
    for (int p = 0; p < 4; ++p) { \
        const float ccs = (p < 2) ? cs0c : cs1c; \
        const float scs = (p < 2) ? cs0s : cs1s; \
        const int i0 = (p & 1) * 2; \
        const float cea = (p < 2) ? (CE0)[i0]     : (CE1)[i0]; \
        const float sea = (p < 2) ? (SE0)[i0]     : (SE1)[i0]; \
        const float ceb = (p < 2) ? (CE0)[i0 + 1] : (CE1)[i0 + 1]; \
        const float seb = (p < 2) ? (SE0)[i0 + 1] : (SE1)[i0 + 1]; \
        const float ur0 = fmaf(ccs, cea, -(scs * sea)); \
        const float ui0 = fmaf(ccs, sea,   scs * cea); \
        const float ur1 = fmaf(ccs, ceb, -(scs * seb)); \
        const float ui1 = fmaf(ccs, seb,   scs * ceb); \
        hr[p] = pkrtz_u(ur0, ur1); \
        hi[p] = pkrtz_u(ui0, ui1); \
        lr[p] = pkrtz_u(fmix_sub_lo(hr[p], ur0), fmix_sub_hi(hr[p], ur1)); \
        li[p] = pkrtz_u(fmix_sub_lo(hi[p], ui0), fmix_sub_hi(hi[p], ui1)); \
    } \
    const f16x8 ahr = pack8(hr[0], hr[1], hr[2], hr[3]); \
    const f16x8 ahi = pack8(hi[0], hi[1], hi[2], hi[3]); \
    const f16x8 alr = pack8(lr[0], lr[1], lr[2], lr[3]); \
    const f16x8 ali = pack8(li[0], li[1], li[2], li[3]); \
    acc_r[0] = __builtin_amdgcn_mfma_f32_16x16x32_f16(ahr, BH0, acc_r[0], 0, 0, 0); \
    acc_i[0] = __builtin_amdgcn_mfma_f32_16x16x32_f16(ahi, BH0, acc_i[0], 0, 0, 0); \
    acc_r[1] = __builtin_amdgcn_mfma_f32_16x16x32_f16(ahr, BH1, acc_r[1], 0, 0, 0); \
    acc_i[1] = __builtin_amdgcn_mfma_f32_16x16x32_f16(ahi, BH1, acc_i[1], 0, 0, 0); \
    acc_r[0] = __builtin_amdgcn_mfma_f32_16x16x32_f16(ahr, BL0, acc_r[0], 0, 0, 0); \
    acc_i[0] = __builtin_amdgcn_mfma_f32_16x16x32_f16(ahi, BL0, acc_i[0], 0, 0, 0); \
    acc_r[1] = __builtin_amdgcn_mfma_f32_16x16x32_f16(ahr, BL1, acc_r[1], 0, 0, 0); \
    acc_i[1] = __builtin_amdgcn_mfma_f32_16x16x32_f16(ahi, BL1, acc_i[1], 0, 0, 0); \
    acc_r[0] = __builtin_amdgcn_mfma_f32_16x16x32_f16(alr, BH0, acc_r[0], 0, 0, 0); \
    acc_i[0] = __builtin_amdgcn_mfma_f32_16x16x32_f16(ali, BH0, acc_i[0], 0, 0, 0); \
    acc_r[1] = __builtin_amdgcn_mfma_f32_16x16x32_f16(alr, BH1, acc_r[1], 0, 0, 0); \
    acc_i[1] = __builtin_amdgcn_mfma_f32_16x16x32_f16(ali, BH1, acc_i[1], 0, 0, 0); \
} while (0)

    // ---- pipeline prologue: step-0 state + descriptor for step 1 ----
    f16x8 bh0 = LDB(0), bh1 = LDB(1024), bl0 = LDB(2048), bl1 = LDB(3072);
    float cc0, sc0, cc1, sc1; f32x4 ce0, se0, ce1, se1;
    LOAD_TRIG(LDCT(0), cc0, sc0, ce0, se0, cc1, sc1, ce1, se1);
    u32 stN = LDCT(16);
    ubp += 4096;                         // -> step 1 block

    #pragma unroll 4
    for (int ks = 0; ks < NKSTEP - 1; ++ks) {
        // prefetch step ks+1 (B block at ubp; trig via stN; word for ks+2)
        f16x8 nbh0 = LDB(0), nbh1 = LDB(1024), nbl0 = LDB(2048), nbl1 = LDB(3072);
        float ncc0, nsc0, ncc1, nsc1; f32x4 nce0, nse0, nce1, nse1;
        LOAD_TRIG(stN, ncc0, nsc0, nce0, nse0, ncc1, nsc1, nce1, nse1);
        u32 stN2 = LDCT(32);             // word(ks+2); padded table keeps in-bounds

        COMPUTE_STEP(cc0, sc0, ce0, se0, cc1, sc1, ce1, se1, bh0, bh1, bl0, bl1);

        bh0 = nbh0; bh1 = nbh1; bl0 = nbl0; bl1 = nbl1;
        cc0 = ncc0; sc0 = nsc0; cc1 = ncc1; sc1 = nsc1;
        ce0 = nce0; se0 = nse0; ce1 = nce1; se1 = nse1;
        stN = stN2;
        ubp += 4096; uct += 16;
    }
    // peeled final step (no prefetch, no clamps anywhere)
    COMPUTE_STEP(cc0, sc0, ce0, se0, cc1, sc1, ce1, se1, bh0, bh1, bl0, bl1);

    // ---- epilogue: C/D (m89): col o = oh*16 + (lane&15), row px = 4*lg + q ----
    #pragma unroll
    for (int oh = 0; oh < 2; ++oh) {
        const int o = oh * 16 + lidm;
        const float bo = bias[o];
        #pragma unroll
        for (int q = 0; q < 4; ++q) {
            const int pxr = wv * 16 + lg * 4 + q;
            out[obase + pxr + o * CH_STR] = fast_atan2(acc_i[oh][q], acc_r[oh][q]) + bo;
        }
    }
#undef LDB
#undef LDCT
#undef LOAD_TRIG
#undef COMPUTE_STEP
}

// ---------------------------------------------------------------------------
extern "C" void kernel_launch(void* const* d_in, const int* in_sizes, int n_in,
                              void* d_out, int out_size, void* d_ws, size_t ws_size,
                              hipStream_t stream) {
    const float* x    = (const float*)d_in[0];
    const float* w    = (const float*)d_in[1];
    const float* bias = (const float*)d_in[2];
    float* out        = (float*)d_out;
    _Float16* bfr = (_Float16*)d_ws;                  // 73,728 B
    u32*      ct  = (u32*)((char*)d_ws + 73728);      // 304 B

    {
        int n = NBEL + NCT;
        prep<<<(n + 255) / 256, 256, 0, stream>>>(w, bfr, ct);
    }
    {
        int grid = NPIX / 64;   // 2048 blocks x 4 waves
        mfma_bilinear<<<grid, TPB, 0, stream>>>(x, bfr, ct, bias, out);
    }
}

// Round 22
// 47.045 us; speedup vs baseline: 1.0740x; 1.0355x over previous
//
#include <hip/hip_runtime.h>
#include <math.h>

typedef float        f32x4 __attribute__((ext_vector_type(4)));
typedef _Float16     f16x2 __attribute__((ext_vector_type(2)));
typedef _Float16     f16x8 __attribute__((ext_vector_type(8)));
typedef unsigned int u32;
typedef unsigned int u32x4 __attribute__((ext_vector_type(4)));

// Problem constants
#define HW_    4096
#define CH_STR 8192          // channel (or o) stride in x/out = D*HW
#define B_STR  262144        // batch stride = C*D*HW
#define NPIX   131072
#define NKSTEP 18            // 576 rlen4-padded k-slots / 32
#define NSLICE 72            // 576 / 8
#define NCT    76            // +1 step pad for 2-deep descriptor prefetch
#define NBEL   (NKSTEP*2*2*64*8)   // 36864 frag elems (73,728 B)

// Scales: trig pre-scaled by 32 on BOTH sides (validated R18) -> u' = 1024*u;
// w' = 512*w -> acc = 2^19*oc; atan2 scale-invariant. fp16 splits stay normal.
#define WSCALE 512.0f
#define TSCALE 32.0f

// d_ws: frag _Float16[36864] at +0 (73,728 B); ct u32[76] at +73728 (304 B).

// ---------------------------------------------------------------------------
// Prep (validated R16-R20: absmax 0.015625). Rows c padded to rlen4(c)=
// 4*(c/4+1) (total 576). frag[ks][var*2+oh][lane][j]: fp16 RNE split of
// 512*foldW at k = ks*32+8*(lane>>4)+j, o = oh*16+(lane&15).
// ct[s] = (cB0<<24)|(eB0<<16)|(cB1<<8)|eB1 byte offsets for slice s's two
// 4-segments. Zero-padded to 76 words.
// ---------------------------------------------------------------------------
__global__ void prep(const float* __restrict__ w,
                     _Float16* __restrict__ bfr,
                     u32* __restrict__ ct) {
    int idx = blockIdx.x * 256 + threadIdx.x;
    if (idx < NBEL) {
        int j    =  idx & 7;
        int lane = (idx >> 3) & 63;
        int frag = (idx >> 9) & 3;      // var*2 + oh
        int ks   =  idx >> 11;
        int var  = frag >> 1;
        int oh   = frag & 1;
        int k = ks * 32 + ((lane >> 4) << 3) + j;
        int c = 0, base = 0;
        for (; c < 32; ++c) { int rl = ((c >> 2) + 1) << 2; if (k < base + rl) break; base += rl; }
        int e = k - base;
        int o = oh * 16 + (lane & 15);
        float v = 0.0f;
        if (e <= c)
            v = (e == c) ? w[o * 1024 + c * 33]
                         : (w[o * 1024 + c * 32 + e] + w[o * 1024 + e * 32 + c]);
        v *= WSCALE;
        _Float16 h = (_Float16)v;                    // RNE hi
        if (var) h = (_Float16)(v - (float)h);       // RNE residual (lo)
        bfr[idx] = h;
    } else if (idx < NBEL + NCT) {
        int s = idx - NBEL;
        u32 v = 0;
        if (s < NSLICE) {
            int cb[2], eb[2];
            #pragma unroll
            for (int h = 0; h < 2; ++h) {
                int k = s * 8 + h * 4, c = 0, base = 0;
                for (; c < 32; ++c) { int rl = ((c >> 2) + 1) << 2; if (k < base + rl) break; base += rl; }
                cb[h] = c * 4; eb[h] = (k - base) * 4;
            }
            v = ((u32)cb[0] << 24) | ((u32)eb[0] << 16) | ((u32)cb[1] << 8) | (u32)eb[1];
        }
        ct[s] = v;
    }
}

// ---------------------------------------------------------------------------
// Main. R21 = R20 (best: 42.5 us kernel) + two micro-cuts:
//  (1) prologue channel order c = 4m+lg: sincos LDS writes land at bank
//      == lg (mod 4) per lane group -> <=2 lanes/bank (free), killing the
//      8-way write conflicts (bank = 4*lidm + 8*lg + m collided).
//  (2) trig pre-scaled by 32 (both sides, R18-validated numerics) -> the 4
//      per-step USCALE mults are gone.
// ---------------------------------------------------------------------------
#define TPB   256
#define TSTR  68    // trig row stride (dwords) = 272 B, multiple of 16

__device__ __forceinline__ f16x8 pack8(u32 a, u32 b, u32 c, u32 d) {
    u32x4 t = {a, b, c, d};
    return __builtin_bit_cast(f16x8, t);
}
__device__ __forceinline__ u32 pkrtz_u(float a, float b) {
    return __builtin_bit_cast(u32, __builtin_amdgcn_cvt_pkrtz(a, b));
}

// ul = u - (f32)(f16 half of H)   [exact; Sterbenz], one VALU op (R20-validated).
__device__ __forceinline__ float fmix_sub_lo(u32 H, float u) {
    float r;
    asm("v_fma_mix_f32 %0, %1, -1.0, %2 op_sel:[0,0,0] op_sel_hi:[1,0,0]"
        : "=v"(r) : "v"(H), "v"(u));
    return r;
}
__device__ __forceinline__ float fmix_sub_hi(u32 H, float u) {
    float r;
    asm("v_fma_mix_f32 %0, %1, -1.0, %2 op_sel:[1,0,0] op_sel_hi:[1,0,0]"
        : "=v"(r) : "v"(H), "v"(u));
    return r;
}

// Branch-free atan2 (validated R17): ~17 VALU, err ~1e-6 rad.
__device__ __forceinline__ float fast_atan2(float y, float x) {
    const float ax = __builtin_fabsf(x), ay = __builtin_fabsf(y);
    const float mx = fmaxf(ax, ay), mn = fminf(ax, ay);
    const float t  = mn * __builtin_amdgcn_rcpf(fmaxf(mx, 1e-37f));
    const float s  = t * t;
    float p = fmaf(s, -0.0117212f, 0.05265332f);
    p = fmaf(s, p, -0.11643287f);
    p = fmaf(s, p,  0.19354346f);
    p = fmaf(s, p, -0.33262347f);
    p = fmaf(s, p,  0.99997726f);
    float a = t * p;
    a = (ay > ax) ? (1.5707963268f - a) : a;
    a = (x < 0.0f) ? (3.1415926536f - a) : a;
    return __builtin_copysignf(a, y);
}

__global__ __launch_bounds__(TPB, 4) void mfma_bilinear(
    const float* __restrict__ x,
    const _Float16* __restrict__ bfr,
    const u32* __restrict__ ct,
    const float* __restrict__ bias,
    float* __restrict__ out)
{
    __shared__ float trig[64 * TSTR];   // 17,408 B

    const int lane = threadIdx.x & 63;
    const int wv   = threadIdx.x >> 6;       // wave id 0..3
    const int lg   = lane >> 4;              // k-subgroup 0..3
    const int lidm = lane & 15;              // A-row / B-col within fragment
    const int P0   = blockIdx.x * 64;
    const int b    = P0 >> 13;
    const int d    = (P0 >> 12) & 1;
    const int hw0  = P0 & 4095;              // 64-aligned, block stays in (b,d)
    const int obase = b * B_STR + d * HW_ + hw0;   // + px + (c|o)*CH_STR

    const int px = wv * 16 + lidm;           // block-local pixel (my A-row)
    float* tp = trig + px * TSTR;
    const char* tb = (const char*)tp;        // byte base of my trig row

    // ---- trig prologue: c = 4m+lg -> conflict-free LDS writes; x32 scale ----
    #pragma unroll
    for (int m = 0; m < 8; ++m) {
        int c = (m << 2) + lg;
        float xv = x[obase + px + c * CH_STR];
        float s, co; __sincosf(xv, &s, &co);
        tp[c]      = co * TSCALE;
        tp[32 + c] = s * TSCALE;
    }
    // same-wave DS ordering makes the reads below safe without a barrier.

    f32x4 acc_r[2] = {{0.f,0.f,0.f,0.f}, {0.f,0.f,0.f,0.f}};
    f32x4 acc_i[2] = {{0.f,0.f,0.f,0.f}, {0.f,0.f,0.f,0.f}};

    // Streaming pointers: uniform base + (lane/lg) voffset + imm offsets.
    const char* ubp = (const char*)bfr;      // step-ks B block at ubp (+= 4096)
    const char* uct = (const char*)ct;       // word(ks) at uct (+= 16)
    const int lo16 = lane * 16;
    const int lg4  = lg * 4;

#define LDB(OFF)      (*(const f16x8*)(ubp + lo16 + (OFF)))
#define LDCT(OFF)     (*(const u32*)(uct + lg4 + (OFF)))
#define LOAD_TRIG(ST, CC0, SC0, CE0, SE0, CC1, SC1, CE1, SE1) do { \
    const u32 st_ = (ST); \
    const int cB0 = (int)(st_ >> 24); \
    const int eB0 = (int)((st_ >> 16) & 0xffu); \
    const int cB1 = (int)((st_ >> 8) & 0xffu); \
    const int eB1 = (int)(st_ & 0xffu); \
    CC0 = *(const float*)(tb + cB0); \
    SC0 = *(const float*)(tb + 128 + cB0); \
    CE0 = *(const f32x4*)(tb + eB0); \
    SE0 = *(const f32x4*)(tb + 128 + eB0); \
    CC1 = *(const float*)(tb + cB1); \
    SC1 = *(const float*)(tb + 128 + cB1); \
    CE1 = *(const f32x4*)(tb + eB1); \
    SE1 = *(const f32x4*)(tb + 128 + eB1); \
} while (0)

// One k-step: u-gen (pre-scaled trig) + fp16 split (fma_mix) + 12 MFMA.
#define COMPUTE_STEP(CC0, SC0, CE0, SE0, CC1, SC1, CE1, SE1, BH0, BH1, BL0, BL1) do { \
    u32 hr[4], hi[4], lr[4], li[4]; \
    _Pragma("unroll") \
    for (int p = 0; p < 4; ++p) { \
        const float ccs = (p < 2) ? (CC0) : (CC1); \
        const float scs = (p < 2) ? (SC0) : (SC1); \
        const int i0 = (p & 1) * 2; \
        const float cea = (p < 2) ? (CE0)[i0]     : (CE1)[i0]; \
        const float sea = (p < 2) ? (SE0)[i0]     : (SE1)[i0]; \
        const float ceb = (p < 2) ? (CE0)[i0 + 1] : (CE1)[i0 + 1]; \
        const float seb = (p < 2) ? (SE0)[i0 + 1] : (SE1)[i0 + 1]; \
        const float ur0 = fmaf(ccs, cea, -(scs * sea)); \
        const float ui0 = fmaf(ccs, sea,   scs * cea); \
        const float ur1 = fmaf(ccs, ceb, -(scs * seb)); \
        const float ui1 = fmaf(ccs, seb,   scs * ceb); \
        hr[p] = pkrtz_u(ur0, ur1); \
        hi[p] = pkrtz_u(ui0, ui1); \
        lr[p] = pkrtz_u(fmix_sub_lo(hr[p], ur0), fmix_sub_hi(hr[p], ur1)); \
        li[p] = pkrtz_u(fmix_sub_lo(hi[p], ui0), fmix_sub_hi(hi[p], ui1)); \
    } \
    const f16x8 ahr = pack8(hr[0], hr[1], hr[2], hr[3]); \
    const f16x8 ahi = pack8(hi[0], hi[1], hi[2], hi[3]); \
    const f16x8 alr = pack8(lr[0], lr[1], lr[2], lr[3]); \
    const f16x8 ali = pack8(li[0], li[1], li[2], li[3]); \
    acc_r[0] = __builtin_amdgcn_mfma_f32_16x16x32_f16(ahr, BH0, acc_r[0], 0, 0, 0); \
    acc_i[0] = __builtin_amdgcn_mfma_f32_16x16x32_f16(ahi, BH0, acc_i[0], 0, 0, 0); \
    acc_r[1] = __builtin_amdgcn_mfma_f32_16x16x32_f16(ahr, BH1, acc_r[1], 0, 0, 0); \
    acc_i[1] = __builtin_amdgcn_mfma_f32_16x16x32_f16(ahi, BH1, acc_i[1], 0, 0, 0); \
    acc_r[0] = __builtin_amdgcn_mfma_f32_16x16x32_f16(ahr, BL0, acc_r[0], 0, 0, 0); \
    acc_i[0] = __builtin_amdgcn_mfma_f32_16x16x32_f16(ahi, BL0, acc_i[0], 0, 0, 0); \
    acc_r[1] = __builtin_amdgcn_mfma_f32_16x16x32_f16(ahr, BL1, acc_r[1], 0, 0, 0); \
    acc_i[1] = __builtin_amdgcn_mfma_f32_16x16x32_f16(ahi, BL1, acc_i[1], 0, 0, 0); \
    acc_r[0] = __builtin_amdgcn_mfma_f32_16x16x32_f16(alr, BH0, acc_r[0], 0, 0, 0); \
    acc_i[0] = __builtin_amdgcn_mfma_f32_16x16x32_f16(ali, BH0, acc_i[0], 0, 0, 0); \
    acc_r[1] = __builtin_amdgcn_mfma_f32_16x16x32_f16(alr, BH1, acc_r[1], 0, 0, 0); \
    acc_i[1] = __builtin_amdgcn_mfma_f32_16x16x32_f16(ali, BH1, acc_i[1], 0, 0, 0); \
} while (0)

    // ---- pipeline prologue: step-0 state + descriptor for step 1 ----
    f16x8 bh0 = LDB(0), bh1 = LDB(1024), bl0 = LDB(2048), bl1 = LDB(3072);
    float cc0, sc0, cc1, sc1; f32x4 ce0, se0, ce1, se1;
    LOAD_TRIG(LDCT(0), cc0, sc0, ce0, se0, cc1, sc1, ce1, se1);
    u32 stN = LDCT(16);
    ubp += 4096;                         // -> step 1 block

    #pragma unroll 4
    for (int ks = 0; ks < NKSTEP - 1; ++ks) {
        // prefetch step ks+1 (B block at ubp; trig via stN; word for ks+2)
        f16x8 nbh0 = LDB(0), nbh1 = LDB(1024), nbl0 = LDB(2048), nbl1 = LDB(3072);
        float ncc0, nsc0, ncc1, nsc1; f32x4 nce0, nse0, nce1, nse1;
        LOAD_TRIG(stN, ncc0, nsc0, nce0, nse0, ncc1, nsc1, nce1, nse1);
        u32 stN2 = LDCT(32);             // word(ks+2); padded table keeps in-bounds

        COMPUTE_STEP(cc0, sc0, ce0, se0, cc1, sc1, ce1, se1, bh0, bh1, bl0, bl1);

        bh0 = nbh0; bh1 = nbh1; bl0 = nbl0; bl1 = nbl1;
        cc0 = ncc0; sc0 = nsc0; cc1 = ncc1; sc1 = nsc1;
        ce0 = nce0; se0 = nse0; ce1 = nce1; se1 = nse1;
        stN = stN2;
        ubp += 4096; uct += 16;
    }
    // peeled final step (no prefetch, no clamps anywhere)
    COMPUTE_STEP(cc0, sc0, ce0, se0, cc1, sc1, ce1, se1, bh0, bh1, bl0, bl1);

    // ---- epilogue: C/D (m89): col o = oh*16 + (lane&15), row px = 4*lg + q ----
    #pragma unroll
    for (int oh = 0; oh < 2; ++oh) {
        const int o = oh * 16 + lidm;
        const float bo = bias[o];
        #pragma unroll
        for (int q = 0; q < 4; ++q) {
            const int pxr = wv * 16 + lg * 4 + q;
            out[obase + pxr + o * CH_STR] = fast_atan2(acc_i[oh][q], acc_r[oh][q]) + bo;
        }
    }
#undef LDB
#undef LDCT
#undef LOAD_TRIG
#undef COMPUTE_STEP
}

// ---------------------------------------------------------------------------
extern "C" void kernel_launch(void* const* d_in, const int* in_sizes, int n_in,
                              void* d_out, int out_size, void* d_ws, size_t ws_size,
                              hipStream_t stream) {
    const float* x    = (const float*)d_in[0];
    const float* w    = (const float*)d_in[1];
    const float* bias = (const float*)d_in[2];
    float* out        = (float*)d_out;
    _Float16* bfr = (_Float16*)d_ws;                  // 73,728 B
    u32*      ct  = (u32*)((char*)d_ws + 73728);      // 304 B

    {
        int n = NBEL + NCT;
        prep<<<(n + 255) / 256, 256, 0, stream>>>(w, bfr, ct);
    }
    {
        int grid = NPIX / 64;   // 2048 blocks x 4 waves
        mfma_bilinear<<<grid, TPB, 0, stream>>>(x, bfr, ct, bias, out);
    }
}